// Round 12
// baseline (73.431 us; speedup 1.0000x reference)
//
#include <hip/hip_runtime.h>
#include <hip/hip_bf16.h>

// GraphAttentionLayer collapse: out[b,i,o] = (S_mask[b,i,o] < 0) ? 1 : 0,
// S_mask = sum_{adj[i,j]==0} hW[b,j,o]  (|9e15*S_mask| >> |softmax term| => sigmoid saturates).
// Exact i8 MFMA path:
//   q = rint(hW*2^16) = d0 + 256*d1 + 65536*d2, balanced digits in [-128,127] (exact i8).
//   mask bit 0/1 exact i8; i32 MFMA accumulation exact.
//   S = c0 + 256*c1 + 65536*c2 (f64, exact integers). |S| > 2048 => sign reliable;
//   else exact f64 recompute in-block.
// ROUND-11 BUG FIX: W->LDS staging copied only 8*256=2048 of the 8192 W elements
// (rows 0..31); rows 32..127 were poison -> wrong hW -> wrong signs. Loop bound
// is 32 elements/thread. Everything else unchanged from R11 (= R10 gemm verbatim).

#define GN 4096
#define GB 4
#define FIN 128
#define FOUT 64

typedef int i32x4 __attribute__((ext_vector_type(4)));
typedef unsigned int uint32x4 __attribute__((ext_vector_type(4)));
typedef float f32x4 __attribute__((ext_vector_type(4)));
typedef float f32x2 __attribute__((ext_vector_type(2)));

// ---- kernel 1: adj -> transposed bitmask tmask[(rt*64+s)*64 + l] (u64) ----
// bit (r*16+jj) of tmask[rt*64+s][l] = (adj[rt*64 + r*16 + (l&15)][s*64 + (l>>4)*16 + jj] == 0)
// (R2..R8-verified gather: each instr = 16 full 64B-line segments)
__global__ __launch_bounds__(256) void pack_kernel(const int* __restrict__ adj,
                                                   unsigned long long* __restrict__ tmask) {
    int wid = blockIdx.x * 4 + (threadIdx.x >> 6);
    int lane = threadIdx.x & 63;
    int rt = wid >> 6, s = wid & 63;
    int row16 = lane & 15, g = lane >> 4;
    const int* base = adj + (size_t)(rt * 64 + row16) * GN + s * 64 + g * 16;
    unsigned long long res = 0ull;
#pragma unroll
    for (int r = 0; r < 4; ++r) {
        const i32x4* p = (const i32x4*)(base + (size_t)r * 16 * GN);
        unsigned int b16 = 0;
#pragma unroll
        for (int q = 0; q < 4; ++q) {
            i32x4 v = p[q];
            b16 |= (v.x == 0 ? 1u : 0u) << (q * 4);
            b16 |= (v.y == 0 ? 2u : 0u) << (q * 4);
            b16 |= (v.z == 0 ? 4u : 0u) << (q * 4);
            b16 |= (v.w == 0 ? 8u : 0u) << (q * 4);
        }
        res |= (unsigned long long)b16 << (r * 16);
    }
    tmask[(size_t)wid * 64 + lane] = res;
}

// ---- kernel 2: hW = h @ W (f64) + fused digit-plane packing, ILP version ----
// W converted ONCE per block to f64 in LDS (ALL 8192 elems: 32/thread); k-loop is
// pure LDS+fma_f64. Bp layout verified R7..R10.
__global__ __launch_bounds__(256, 1) void hwrepack_kernel(const float* __restrict__ h,
                                                          const float* __restrict__ W,
                                                          double* __restrict__ hW,
                                                          unsigned char* __restrict__ Bp) {
    __shared__ double Wd[FIN][FOUT];    // 64 KB
    __shared__ double hsd[4][FIN];      // 4 KB
    __shared__ unsigned int dg[4][64];  // 1 KB

    const int grp = threadIdx.x >> 6;
    const int o = threadIdx.x & 63;
    const int b = (int)blockIdx.x >> 10, q4 = (int)blockIdx.x & 1023;

    // stage W -> f64 LDS (coalesced, 32 elems/thread: 32*256 = 8192 = FIN*FOUT)
#pragma unroll
    for (int c = 0; c < 32; ++c) {
        int idx = c * 256 + threadIdx.x;
        Wd[idx >> 6][idx & 63] = (double)W[idx];
    }
    // stage 4 rows of h as f64 (2 cvts/thread)
    {
        const f32x2* src = (const f32x2*)(h + ((size_t)b * GN + q4 * 4) * FIN);
        f32x2 v = src[threadIdx.x];
        double* drow = &hsd[threadIdx.x >> 6][(threadIdx.x & 63) * 2];
        drow[0] = (double)v.x;
        drow[1] = (double)v.y;
    }
    __syncthreads();

    double a0 = 0, a1 = 0, a2 = 0, a3 = 0;
#pragma unroll
    for (int i = 0; i < FIN; i += 4) {
        a0 = fma(hsd[grp][i],     Wd[i][o],     a0);
        a1 = fma(hsd[grp][i + 1], Wd[i + 1][o], a1);
        a2 = fma(hsd[grp][i + 2], Wd[i + 2][o], a2);
        a3 = fma(hsd[grp][i + 3], Wd[i + 3][o], a3);
    }
    double acc = (a0 + a1) + (a2 + a3);
    hW[((size_t)b * GN + q4 * 4 + grp) * FOUT + o] = acc;

    int qi = (int)llrint(acc * 65536.0);
    int d0 = ((qi + 128) & 255) - 128; qi = (qi - d0) >> 8;
    int d1 = ((qi + 128) & 255) - 128; qi = (qi - d1) >> 8;  // qi now = d2
    dg[grp][o] = (unsigned int)(d0 & 255) | ((unsigned int)(d1 & 255) << 8)
               | ((unsigned int)(qi & 255) << 16);
    __syncthreads();
    if (grp < 3) {   // grp = digit plane
        unsigned int w = 0;
#pragma unroll
        for (int rr = 0; rr < 4; ++rr)
            w |= ((dg[rr][o] >> (grp * 8)) & 255u) << (rr * 8);
        const int p = q4 >> 4, g = (q4 >> 2) & 3, qr = q4 & 3;
        const int cg = o >> 4, col16 = o & 15;
        *(unsigned int*)(Bp + ((size_t)b * 64 + p) * 12288 + grp * 4096
                         + cg * 1024 + g * 256 + col16 * 16 + qr * 4) = w;
    }
}

// ---- kernel 3: exact i8-MFMA masked-sum GEMM, depth-4 register pipeline (R10) ----
__global__ __launch_bounds__(512, 1) void gemm_kernel(const unsigned char* __restrict__ Bp,
                                                      const unsigned long long* __restrict__ tmask,
                                                      const double* __restrict__ hW,
                                                      float* __restrict__ out) {
    __shared__ __align__(16) unsigned char lds[49152];   // kg-merge
    __shared__ unsigned int nflag;
    __shared__ unsigned int flagbuf[128];
    __shared__ double fred[8];

    const int tid = threadIdx.x, lane = tid & 63, wv = tid >> 6;
    const int cg = wv & 3, kg = wv >> 2;
    const int rt = (int)blockIdx.x >> 2, b = (int)blockIdx.x & 3;
    if (tid == 0) nflag = 0;

    const unsigned char* bptr = Bp + (size_t)b * 786432 + kg * 12288 + cg * 1024 + lane * 16;
    const unsigned long long* mptr = tmask + (size_t)rt * 4096 + kg * 64 + lane;

    i32x4 acc[4][3];
#pragma unroll
    for (int r = 0; r < 4; ++r)
#pragma unroll
        for (int pl = 0; pl < 3; ++pl) {
            i32x4 z = {0, 0, 0, 0};
            acc[r][pl] = z;
        }

#define DECLSET(S) i32x4 b##S##0, b##S##1, b##S##2; unsigned long long m##S;
#define LOADSET(S, T) { const unsigned char* g_ = bptr + (size_t)(T) * 24576;          \
        b##S##0 = *(const i32x4*)(g_);                                                 \
        b##S##1 = *(const i32x4*)(g_ + 4096);                                          \
        b##S##2 = *(const i32x4*)(g_ + 8192);                                          \
        m##S = mptr[(size_t)(T) * 128]; }

    DECLSET(A) DECLSET(B) DECLSET(C) DECLSET(D)
    LOADSET(A, 0) LOADSET(B, 1) LOADSET(C, 2) LOADSET(D, 3)

    auto dostep = [&](unsigned long long mw, i32x4 v0, i32x4 v1, i32x4 v2) {
        const unsigned int mlo = (unsigned int)mw, mhi = (unsigned int)(mw >> 32);
#pragma unroll
        for (int r = 0; r < 4; ++r) {
            unsigned int half = (r >> 1) ? mhi : mlo;
            unsigned int w16 = (r & 1) ? (half >> 16) : (half & 0xFFFFu);
            uint32x4 u;
#pragma unroll
            for (int q = 0; q < 4; ++q)
                u[q] = (((w16 >> (4 * q)) & 0xFu) * 0x00204081u) & 0x01010101u;
            i32x4 af = __builtin_bit_cast(i32x4, u);
            acc[r][0] = __builtin_amdgcn_mfma_i32_16x16x64_i8(af, v0, acc[r][0], 0, 0, 0);
            acc[r][1] = __builtin_amdgcn_mfma_i32_16x16x64_i8(af, v1, acc[r][1], 0, 0, 0);
            acc[r][2] = __builtin_amdgcn_mfma_i32_16x16x64_i8(af, v2, acc[r][2], 0, 0, 0);
        }
    };

    for (int T = 0; T < 32; T += 4) {
        dostep(mA, bA0, bA1, bA2);
        if (T + 4 < 32) LOADSET(A, T + 4)
        dostep(mB, bB0, bB1, bB2);
        if (T + 5 < 32) LOADSET(B, T + 5)
        dostep(mC, bC0, bC1, bC2);
        if (T + 6 < 32) LOADSET(C, T + 6)
        dostep(mD, bD0, bD1, bD2);
        if (T + 7 < 32) LOADSET(D, T + 7)
    }
#undef DECLSET
#undef LOADSET

    // merge kg=1 partials into kg=0 via LDS
    __syncthreads();
    if (kg == 1) {
        unsigned char* dst = lds + cg * 12288 + lane * 192;
#pragma unroll
        for (int r = 0; r < 4; ++r)
#pragma unroll
            for (int pl = 0; pl < 3; ++pl)
                *(i32x4*)(dst + (r * 3 + pl) * 16) = acc[r][pl];
    }
    __syncthreads();
    if (kg == 0) {
        const unsigned char* s2 = lds + cg * 12288 + lane * 192;
#pragma unroll
        for (int r = 0; r < 4; ++r)
#pragma unroll
            for (int pl = 0; pl < 3; ++pl) {
                i32x4 v = *(const i32x4*)(s2 + (r * 3 + pl) * 16);
#pragma unroll
                for (int q = 0; q < 4; ++q) acc[r][pl][q] += v[q];
            }

        const int o = cg * 16 + (lane & 15);
#pragma unroll
        for (int r = 0; r < 4; ++r) {
#pragma unroll
            for (int q = 0; q < 4; ++q) {
                double S = (double)acc[r][0][q] + 256.0 * (double)acc[r][1][q]
                         + 65536.0 * (double)acc[r][2][q];     // exact integer
                int i = rt * 64 + r * 16 + (lane >> 4) * 4 + q;  // C/D row map (m89)
                size_t oi = ((size_t)b * GN + i) * FOUT + o;
                out[oi] = S < 0.0 ? 1.0f : 0.0f;
                if (fabs(S) <= 2048.0) {
                    unsigned int idx = atomicAdd(&nflag, 1u);
                    if (idx < 128) flagbuf[idx] = ((unsigned int)i << 6) | (unsigned int)o;
                }
            }
        }
    }

    // ---- in-block exact fixup (expected ~0.2 items/block) ----
    __syncthreads();
    unsigned int nf = nflag;
    if (nf > 128) nf = 128;
    for (unsigned int f = 0; f < nf; ++f) {
        unsigned int e = flagbuf[f];
        int o = e & 63;
        int i = (int)(e >> 6);
        int row16 = i & 15, r = (i >> 4) & 3;
        int s = tid >> 3, lg = (tid >> 1) & 3, hf = tid & 1;
        unsigned long long w = tmask[((size_t)rt * 64 + s) * 64 + (lg * 16 + row16)];
        double ps = 0.0;
        const double* hwc = hW + ((size_t)b * GN + s * 64 + lg * 16) * FOUT + o;
#pragma unroll
        for (int jj = hf * 8; jj < hf * 8 + 8; ++jj) {
            if ((w >> (r * 16 + jj)) & 1ull)
                ps += hwc[(size_t)jj * FOUT];
        }
#pragma unroll
        for (int d = 32; d >= 1; d >>= 1) ps += __shfl_down(ps, d, 64);
        if (lane == 0) fred[wv] = ps;
        __syncthreads();
        if (tid == 0) {
            double tot = ((fred[0] + fred[1]) + (fred[2] + fred[3]))
                       + ((fred[4] + fred[5]) + (fred[6] + fred[7]));
            out[((size_t)b * GN + i) * FOUT + o] = tot < 0.0 ? 1.0f : 0.0f;
        }
        __syncthreads();
    }
}

extern "C" void kernel_launch(void* const* d_in, const int* in_sizes, int n_in,
                              void* d_out, int out_size, void* d_ws, size_t ws_size,
                              hipStream_t stream) {
    const float* h   = (const float*)d_in[0];   // [4,4096,128]
    const int*   adj = (const int*)d_in[1];     // [4096,4096]
    const float* W   = (const float*)d_in[2];   // [128,64]
    float* out = (float*)d_out;                 // [4,4096,64] f32

    char* ws = (char*)d_ws;
    double* hW                = (double*)ws;                          // 8 MB @ 0
    unsigned char* Bp         = (unsigned char*)(ws + 8388608);       // 3 MB @ 8M
    unsigned long long* tmask = (unsigned long long*)(ws + 12582912); // 2 MB @ 12M

    pack_kernel<<<1024, 256, 0, stream>>>(adj, tmask);
    hwrepack_kernel<<<4096, 256, 0, stream>>>(h, W, hW, Bp);
    gemm_kernel<<<256, 512, 0, stream>>>(Bp, tmask, hW, out);
}

// Round 13
// 61.235 us; speedup vs baseline: 1.1992x; 1.1992x over previous
//
#include <hip/hip_runtime.h>
#include <hip/hip_bf16.h>

// GraphAttentionLayer collapse: out[b,i,o] = (S_mask[b,i,o] < 0) ? 1 : 0,
// S_mask = sum_{adj[i,j]==0} hW[b,j,o]  (|9e15*S_mask| >> |softmax term| => sigmoid saturates).
// Exact i8 MFMA path:
//   q = rint(hW*2^16) = d0 + 256*d1 + 65536*d2, balanced digits in [-128,127] (exact i8).
//   mask bit 0/1 exact i8; i32 MFMA accumulation exact.
//   S = c0 + 256*c1 + 65536*c2 (f64, exact integers). |S| > 2048 => sign reliable;
//   else exact f64 recompute in-block.
// Round-13: hwrepack v3. R12's 40us cause: BOTH k-loop operands from LDS (256 ds_read_b64
// /thread) + 69KB LDS (2 blk/CU) + 8 block-rounds re-staging W. v3: W as f32 in LDS
// (128 ds_read_b32/thread, 2-way=free), h via wave-uniform scalar loads (no LDS),
// 4 rows/thread (W read+cvt amortized 4x, no digit exchange). pack/gemm unchanged.

#define GN 4096
#define GB 4
#define FIN 128
#define FOUT 64

typedef int i32x4 __attribute__((ext_vector_type(4)));
typedef unsigned int uint32x4 __attribute__((ext_vector_type(4)));
typedef float f32x4 __attribute__((ext_vector_type(4)));

// ---- kernel 1: adj -> transposed bitmask tmask[(rt*64+s)*64 + l] (u64) ----
// bit (r*16+jj) of tmask[rt*64+s][l] = (adj[rt*64 + r*16 + (l&15)][s*64 + (l>>4)*16 + jj] == 0)
__global__ __launch_bounds__(256) void pack_kernel(const int* __restrict__ adj,
                                                   unsigned long long* __restrict__ tmask) {
    int wid = blockIdx.x * 4 + (threadIdx.x >> 6);
    int lane = threadIdx.x & 63;
    int rt = wid >> 6, s = wid & 63;
    int row16 = lane & 15, g = lane >> 4;
    const int* base = adj + (size_t)(rt * 64 + row16) * GN + s * 64 + g * 16;
    unsigned long long res = 0ull;
#pragma unroll
    for (int r = 0; r < 4; ++r) {
        const i32x4* p = (const i32x4*)(base + (size_t)r * 16 * GN);
        unsigned int b16 = 0;
#pragma unroll
        for (int q = 0; q < 4; ++q) {
            i32x4 v = p[q];
            b16 |= (v.x == 0 ? 1u : 0u) << (q * 4);
            b16 |= (v.y == 0 ? 2u : 0u) << (q * 4);
            b16 |= (v.z == 0 ? 4u : 0u) << (q * 4);
            b16 |= (v.w == 0 ? 8u : 0u) << (q * 4);
        }
        res |= (unsigned long long)b16 << (r * 16);
    }
    tmask[(size_t)wid * 64 + lane] = res;
}

// ---- kernel 2: hW = h @ W (f64) + digit planes, v3 ----
// 1024 blocks x 256 thr; block = 16 rows (batch b = bx>>8, rows (bx&255)*16..+15).
// Thread (a = t>>6, o = t&63): rows row0..row0+3, row0 = (bx&255)*16 + a*4.
// k-loop: Wl[k][o] from LDS f32 (2-way alias, free) + 4 wave-uniform h loads.
// Digits: thread owns 4 consecutive rows = one q4 unit -> builds 3 plane words alone.
// Bp layout (verified R7..R12): Bp[(b*64+p)*12288 + pl*4096 + cg*1024 + g*256 + col16*16 + qr*4].
__global__ __launch_bounds__(256) void hwrepack_kernel(const float* __restrict__ h,
                                                       const float* __restrict__ W,
                                                       double* __restrict__ hW,
                                                       unsigned char* __restrict__ Bp) {
    __shared__ float Wl[FIN][FOUT];     // 32 KB, straight f32 copy
    const int t = threadIdx.x;
    const int o = t & 63, a = t >> 6;
    const int bx = (int)blockIdx.x;
    const int b = bx >> 8, rq = bx & 255;

    {
        const f32x4* Wv = (const f32x4*)W;
        f32x4* Wlv = (f32x4*)&Wl[0][0];
#pragma unroll
        for (int c = 0; c < 8; ++c)
            Wlv[c * 256 + t] = Wv[c * 256 + t];
    }
    __syncthreads();

    const int row0 = rq * 16 + a * 4;
    const float* h0 = h + ((size_t)b * GN + row0) * FIN;   // wave-uniform pointer
    double ac0 = 0, ac1 = 0, ac2 = 0, ac3 = 0;
#pragma unroll 16
    for (int k = 0; k < FIN; ++k) {
        double wd = (double)Wl[k][o];
        ac0 = fma((double)h0[k],           wd, ac0);
        ac1 = fma((double)h0[k + FIN],     wd, ac1);
        ac2 = fma((double)h0[k + 2 * FIN], wd, ac2);
        ac3 = fma((double)h0[k + 3 * FIN], wd, ac3);
    }

    double* hwp = hW + ((size_t)b * GN + row0) * FOUT + o;
    hwp[0]       = ac0;
    hwp[FOUT]    = ac1;
    hwp[2 * FOUT] = ac2;
    hwp[3 * FOUT] = ac3;

    // digits for the 4 rows -> 3 plane words (byte rr = row0+rr)
    unsigned int w0 = 0, w1 = 0, w2 = 0;
    double accs[4] = {ac0, ac1, ac2, ac3};
#pragma unroll
    for (int rr = 0; rr < 4; ++rr) {
        int qi = (int)llrint(accs[rr] * 65536.0);
        int d0 = ((qi + 128) & 255) - 128; qi = (qi - d0) >> 8;
        int d1 = ((qi + 128) & 255) - 128; qi = (qi - d1) >> 8;  // qi now = d2
        w0 |= (unsigned int)(d0 & 255) << (rr * 8);
        w1 |= (unsigned int)(d1 & 255) << (rr * 8);
        w2 |= (unsigned int)(qi & 255) << (rr * 8);
    }
    const int q4 = rq * 4 + a;                // row0 == q4*4
    const int p = q4 >> 4, g = (q4 >> 2) & 3, qr = q4 & 3;
    const int cg = o >> 4, col16 = o & 15;
    unsigned char* dst = Bp + ((size_t)b * 64 + p) * 12288
                       + cg * 1024 + g * 256 + col16 * 16 + qr * 4;
    *(unsigned int*)(dst)        = w0;
    *(unsigned int*)(dst + 4096) = w1;
    *(unsigned int*)(dst + 8192) = w2;
}

// ---- kernel 3: exact i8-MFMA masked-sum GEMM, depth-4 register pipeline (R10) ----
__global__ __launch_bounds__(512, 1) void gemm_kernel(const unsigned char* __restrict__ Bp,
                                                      const unsigned long long* __restrict__ tmask,
                                                      const double* __restrict__ hW,
                                                      float* __restrict__ out) {
    __shared__ __align__(16) unsigned char lds[49152];   // kg-merge
    __shared__ unsigned int nflag;
    __shared__ unsigned int flagbuf[128];
    __shared__ double fred[8];

    const int tid = threadIdx.x, lane = tid & 63, wv = tid >> 6;
    const int cg = wv & 3, kg = wv >> 2;
    const int rt = (int)blockIdx.x >> 2, b = (int)blockIdx.x & 3;
    if (tid == 0) nflag = 0;

    const unsigned char* bptr = Bp + (size_t)b * 786432 + kg * 12288 + cg * 1024 + lane * 16;
    const unsigned long long* mptr = tmask + (size_t)rt * 4096 + kg * 64 + lane;

    i32x4 acc[4][3];
#pragma unroll
    for (int r = 0; r < 4; ++r)
#pragma unroll
        for (int pl = 0; pl < 3; ++pl) {
            i32x4 z = {0, 0, 0, 0};
            acc[r][pl] = z;
        }

#define DECLSET(S) i32x4 b##S##0, b##S##1, b##S##2; unsigned long long m##S;
#define LOADSET(S, T) { const unsigned char* g_ = bptr + (size_t)(T) * 24576;          \
        b##S##0 = *(const i32x4*)(g_);                                                 \
        b##S##1 = *(const i32x4*)(g_ + 4096);                                          \
        b##S##2 = *(const i32x4*)(g_ + 8192);                                          \
        m##S = mptr[(size_t)(T) * 128]; }

    DECLSET(A) DECLSET(B) DECLSET(C) DECLSET(D)
    LOADSET(A, 0) LOADSET(B, 1) LOADSET(C, 2) LOADSET(D, 3)

    auto dostep = [&](unsigned long long mw, i32x4 v0, i32x4 v1, i32x4 v2) {
        const unsigned int mlo = (unsigned int)mw, mhi = (unsigned int)(mw >> 32);
#pragma unroll
        for (int r = 0; r < 4; ++r) {
            unsigned int half = (r >> 1) ? mhi : mlo;
            unsigned int w16 = (r & 1) ? (half >> 16) : (half & 0xFFFFu);
            uint32x4 u;
#pragma unroll
            for (int q = 0; q < 4; ++q)
                u[q] = (((w16 >> (4 * q)) & 0xFu) * 0x00204081u) & 0x01010101u;
            i32x4 af = __builtin_bit_cast(i32x4, u);
            acc[r][0] = __builtin_amdgcn_mfma_i32_16x16x64_i8(af, v0, acc[r][0], 0, 0, 0);
            acc[r][1] = __builtin_amdgcn_mfma_i32_16x16x64_i8(af, v1, acc[r][1], 0, 0, 0);
            acc[r][2] = __builtin_amdgcn_mfma_i32_16x16x64_i8(af, v2, acc[r][2], 0, 0, 0);
        }
    };

    for (int T = 0; T < 32; T += 4) {
        dostep(mA, bA0, bA1, bA2);
        if (T + 4 < 32) LOADSET(A, T + 4)
        dostep(mB, bB0, bB1, bB2);
        if (T + 5 < 32) LOADSET(B, T + 5)
        dostep(mC, bC0, bC1, bC2);
        if (T + 6 < 32) LOADSET(C, T + 6)
        dostep(mD, bD0, bD1, bD2);
        if (T + 7 < 32) LOADSET(D, T + 7)
    }
#undef DECLSET
#undef LOADSET

    // merge kg=1 partials into kg=0 via LDS
    __syncthreads();
    if (kg == 1) {
        unsigned char* dst = lds + cg * 12288 + lane * 192;
#pragma unroll
        for (int r = 0; r < 4; ++r)
#pragma unroll
            for (int pl = 0; pl < 3; ++pl)
                *(i32x4*)(dst + (r * 3 + pl) * 16) = acc[r][pl];
    }
    __syncthreads();
    if (kg == 0) {
        const unsigned char* s2 = lds + cg * 12288 + lane * 192;
#pragma unroll
        for (int r = 0; r < 4; ++r)
#pragma unroll
            for (int pl = 0; pl < 3; ++pl) {
                i32x4 v = *(const i32x4*)(s2 + (r * 3 + pl) * 16);
#pragma unroll
                for (int q = 0; q < 4; ++q) acc[r][pl][q] += v[q];
            }

        const int o = cg * 16 + (lane & 15);
#pragma unroll
        for (int r = 0; r < 4; ++r) {
#pragma unroll
            for (int q = 0; q < 4; ++q) {
                double S = (double)acc[r][0][q] + 256.0 * (double)acc[r][1][q]
                         + 65536.0 * (double)acc[r][2][q];     // exact integer
                int i = rt * 64 + r * 16 + (lane >> 4) * 4 + q;  // C/D row map (m89)
                size_t oi = ((size_t)b * GN + i) * FOUT + o;
                out[oi] = S < 0.0 ? 1.0f : 0.0f;
                if (fabs(S) <= 2048.0) {
                    unsigned int idx = atomicAdd(&nflag, 1u);
                    if (idx < 128) flagbuf[idx] = ((unsigned int)i << 6) | (unsigned int)o;
                }
            }
        }
    }

    // ---- in-block exact fixup (expected ~0.2 items/block) ----
    __syncthreads();
    unsigned int nf = nflag;
    if (nf > 128) nf = 128;
    for (unsigned int f = 0; f < nf; ++f) {
        unsigned int e = flagbuf[f];
        int o = e & 63;
        int i = (int)(e >> 6);
        int row16 = i & 15, r = (i >> 4) & 3;
        int s = tid >> 3, lg = (tid >> 1) & 3, hf = tid & 1;
        unsigned long long w = tmask[((size_t)rt * 64 + s) * 64 + (lg * 16 + row16)];
        double ps = 0.0;
        const double* hwc = hW + ((size_t)b * GN + s * 64 + lg * 16) * FOUT + o;
#pragma unroll
        for (int jj = hf * 8; jj < hf * 8 + 8; ++jj) {
            if ((w >> (r * 16 + jj)) & 1ull)
                ps += hwc[(size_t)jj * FOUT];
        }
#pragma unroll
        for (int d = 32; d >= 1; d >>= 1) ps += __shfl_down(ps, d, 64);
        if (lane == 0) fred[wv] = ps;
        __syncthreads();
        if (tid == 0) {
            double tot = ((fred[0] + fred[1]) + (fred[2] + fred[3]))
                       + ((fred[4] + fred[5]) + (fred[6] + fred[7]));
            out[((size_t)b * GN + i) * FOUT + o] = tot < 0.0 ? 1.0f : 0.0f;
        }
        __syncthreads();
    }
}

extern "C" void kernel_launch(void* const* d_in, const int* in_sizes, int n_in,
                              void* d_out, int out_size, void* d_ws, size_t ws_size,
                              hipStream_t stream) {
    const float* h   = (const float*)d_in[0];   // [4,4096,128]
    const int*   adj = (const int*)d_in[1];     // [4096,4096]
    const float* W   = (const float*)d_in[2];   // [128,64]
    float* out = (float*)d_out;                 // [4,4096,64] f32

    char* ws = (char*)d_ws;
    double* hW                = (double*)ws;                          // 8 MB @ 0
    unsigned char* Bp         = (unsigned char*)(ws + 8388608);       // 3 MB @ 8M
    unsigned long long* tmask = (unsigned long long*)(ws + 12582912); // 2 MB @ 12M

    pack_kernel<<<1024, 256, 0, stream>>>(adj, tmask);
    hwrepack_kernel<<<1024, 256, 0, stream>>>(h, W, hW, Bp);
    gemm_kernel<<<256, 512, 0, stream>>>(Bp, tmask, hW, out);
}

// Round 14
// 55.145 us; speedup vs baseline: 1.3316x; 1.1104x over previous
//
#include <hip/hip_runtime.h>
#include <hip/hip_bf16.h>

// GraphAttentionLayer collapse: out[b,i,o] = (S_mask[b,i,o] < 0) ? 1 : 0,
// S_mask = sum_{adj[i,j]==0} hW[b,j,o]  (|9e15*S_mask| >> |softmax term| => sigmoid saturates).
// Exact i8 MFMA path:
//   q = rint(hW*2^16) = d0 + 256*d1 + 65536*d2, balanced digits in [-128,127] (exact i8).
//   mask bit 0/1 exact i8; i32 MFMA accumulation exact.
//   S = c0 + 256*c1 + 65536*c2 (f64, exact integers). |S| > 2048 => sign reliable;
//   else exact f64 recompute in-block.
// Round-14: hwrepack v6. v3's 28us = 512 per-fma VMEM loads/thread (uniform h reads
// not scalarized) -> VMEM-issue bound (~14us) + LDS + VALU. v6: W column in 128 VGPRs
// (zero per-use memory reads), h as f32 in LDS read via b128 broadcast (128 LDS/thread).
// VALU-bound ~8us predicted. pack/gemm frozen (one-change experiment).

#define GN 4096
#define GB 4
#define FIN 128
#define FOUT 64

typedef int i32x4 __attribute__((ext_vector_type(4)));
typedef unsigned int uint32x4 __attribute__((ext_vector_type(4)));
typedef float f32x4 __attribute__((ext_vector_type(4)));

// ---- kernel 1: adj -> transposed bitmask tmask[(rt*64+s)*64 + l] (u64) ----
// bit (r*16+jj) of tmask[rt*64+s][l] = (adj[rt*64 + r*16 + (l&15)][s*64 + (l>>4)*16 + jj] == 0)
__global__ __launch_bounds__(256) void pack_kernel(const int* __restrict__ adj,
                                                   unsigned long long* __restrict__ tmask) {
    int wid = blockIdx.x * 4 + (threadIdx.x >> 6);
    int lane = threadIdx.x & 63;
    int rt = wid >> 6, s = wid & 63;
    int row16 = lane & 15, g = lane >> 4;
    const int* base = adj + (size_t)(rt * 64 + row16) * GN + s * 64 + g * 16;
    unsigned long long res = 0ull;
#pragma unroll
    for (int r = 0; r < 4; ++r) {
        const i32x4* p = (const i32x4*)(base + (size_t)r * 16 * GN);
        unsigned int b16 = 0;
#pragma unroll
        for (int q = 0; q < 4; ++q) {
            i32x4 v = p[q];
            b16 |= (v.x == 0 ? 1u : 0u) << (q * 4);
            b16 |= (v.y == 0 ? 2u : 0u) << (q * 4);
            b16 |= (v.z == 0 ? 4u : 0u) << (q * 4);
            b16 |= (v.w == 0 ? 8u : 0u) << (q * 4);
        }
        res |= (unsigned long long)b16 << (r * 16);
    }
    tmask[(size_t)wid * 64 + lane] = res;
}

// ---- kernel 2: hW = h @ W (f64) + digit planes, v6 (W-in-VGPRs) ----
// 1024 blocks x 256 thr; block = 16 rows (b = bx>>8, rows (bx&255)*16..+15).
// Thread (a = t>>6, o = t&63): rows row0..row0+3, row0 = (bx&255)*16 + a*4.
// W column o: 128 f32 in VGPRs (staged once, coalesced). h: f32 LDS, b128 broadcast.
// Digits: thread owns 4 consecutive rows = one q4 unit -> builds 3 plane words alone.
// Bp layout (verified R7..R13): Bp[(b*64+p)*12288 + pl*4096 + cg*1024 + g*256 + col16*16 + qr*4].
__global__ __launch_bounds__(256, 1) void hwrepack_kernel(const float* __restrict__ h,
                                                          const float* __restrict__ W,
                                                          double* __restrict__ hW,
                                                          unsigned char* __restrict__ Bp) {
    __shared__ float hsf[16][FIN];      // 8 KB
    const int t = threadIdx.x;
    const int o = t & 63, a = t >> 6;
    const int bx = (int)blockIdx.x;
    const int b = bx >> 8, rq = bx & 255;

    // W column -> 128 VGPRs (coalesced: per k, lanes read 256B contiguous)
    float wreg[128];
#pragma unroll
    for (int k = 0; k < FIN; ++k)
        wreg[k] = W[k * FOUT + o];

    // 16 rows of h -> LDS f32 (2048 f32 = 512 f32x4; 2 per thread)
    {
        const f32x4* src = (const f32x4*)(h + ((size_t)b * GN + rq * 16) * FIN);
        f32x4* dst = (f32x4*)&hsf[0][0];
        dst[t] = src[t];
        dst[t + 256] = src[t + 256];
    }
    __syncthreads();

    const int row0 = rq * 16 + a * 4;
    double ac0 = 0, ac1 = 0, ac2 = 0, ac3 = 0;
#pragma unroll
    for (int k4 = 0; k4 < 32; ++k4) {
        f32x4 h0v = *(const f32x4*)&hsf[a * 4 + 0][k4 * 4];   // b128 broadcast
        f32x4 h1v = *(const f32x4*)&hsf[a * 4 + 1][k4 * 4];
        f32x4 h2v = *(const f32x4*)&hsf[a * 4 + 2][k4 * 4];
        f32x4 h3v = *(const f32x4*)&hsf[a * 4 + 3][k4 * 4];
#pragma unroll
        for (int j = 0; j < 4; ++j) {
            double wd = (double)wreg[k4 * 4 + j];
            ac0 = fma((double)h0v[j], wd, ac0);
            ac1 = fma((double)h1v[j], wd, ac1);
            ac2 = fma((double)h2v[j], wd, ac2);
            ac3 = fma((double)h3v[j], wd, ac3);
        }
    }

    double* hwp = hW + ((size_t)b * GN + row0) * FOUT + o;
    hwp[0]        = ac0;
    hwp[FOUT]     = ac1;
    hwp[2 * FOUT] = ac2;
    hwp[3 * FOUT] = ac3;

    // digits for the 4 rows -> 3 plane words (byte rr = row row0+rr)
    unsigned int w0 = 0, w1 = 0, w2 = 0;
    double accs[4] = {ac0, ac1, ac2, ac3};
#pragma unroll
    for (int rr = 0; rr < 4; ++rr) {
        int qi = (int)llrint(accs[rr] * 65536.0);
        int d0 = ((qi + 128) & 255) - 128; qi = (qi - d0) >> 8;
        int d1 = ((qi + 128) & 255) - 128; qi = (qi - d1) >> 8;  // qi now = d2
        w0 |= (unsigned int)(d0 & 255) << (rr * 8);
        w1 |= (unsigned int)(d1 & 255) << (rr * 8);
        w2 |= (unsigned int)(qi & 255) << (rr * 8);
    }
    const int q4 = rq * 4 + a;                // row0 == q4*4
    const int p = q4 >> 4, g = (q4 >> 2) & 3, qr = q4 & 3;
    const int cg = o >> 4, col16 = o & 15;
    unsigned char* dst = Bp + ((size_t)b * 64 + p) * 12288
                       + cg * 1024 + g * 256 + col16 * 16 + qr * 4;
    *(unsigned int*)(dst)        = w0;
    *(unsigned int*)(dst + 4096) = w1;
    *(unsigned int*)(dst + 8192) = w2;
}

// ---- kernel 3: exact i8-MFMA masked-sum GEMM, depth-4 register pipeline (R10) ----
__global__ __launch_bounds__(512, 1) void gemm_kernel(const unsigned char* __restrict__ Bp,
                                                      const unsigned long long* __restrict__ tmask,
                                                      const double* __restrict__ hW,
                                                      float* __restrict__ out) {
    __shared__ __align__(16) unsigned char lds[49152];   // kg-merge
    __shared__ unsigned int nflag;
    __shared__ unsigned int flagbuf[128];
    __shared__ double fred[8];

    const int tid = threadIdx.x, lane = tid & 63, wv = tid >> 6;
    const int cg = wv & 3, kg = wv >> 2;
    const int rt = (int)blockIdx.x >> 2, b = (int)blockIdx.x & 3;
    if (tid == 0) nflag = 0;

    const unsigned char* bptr = Bp + (size_t)b * 786432 + kg * 12288 + cg * 1024 + lane * 16;
    const unsigned long long* mptr = tmask + (size_t)rt * 4096 + kg * 64 + lane;

    i32x4 acc[4][3];
#pragma unroll
    for (int r = 0; r < 4; ++r)
#pragma unroll
        for (int pl = 0; pl < 3; ++pl) {
            i32x4 z = {0, 0, 0, 0};
            acc[r][pl] = z;
        }

#define DECLSET(S) i32x4 b##S##0, b##S##1, b##S##2; unsigned long long m##S;
#define LOADSET(S, T) { const unsigned char* g_ = bptr + (size_t)(T) * 24576;          \
        b##S##0 = *(const i32x4*)(g_);                                                 \
        b##S##1 = *(const i32x4*)(g_ + 4096);                                          \
        b##S##2 = *(const i32x4*)(g_ + 8192);                                          \
        m##S = mptr[(size_t)(T) * 128]; }

    DECLSET(A) DECLSET(B) DECLSET(C) DECLSET(D)
    LOADSET(A, 0) LOADSET(B, 1) LOADSET(C, 2) LOADSET(D, 3)

    auto dostep = [&](unsigned long long mw, i32x4 v0, i32x4 v1, i32x4 v2) {
        const unsigned int mlo = (unsigned int)mw, mhi = (unsigned int)(mw >> 32);
#pragma unroll
        for (int r = 0; r < 4; ++r) {
            unsigned int half = (r >> 1) ? mhi : mlo;
            unsigned int w16 = (r & 1) ? (half >> 16) : (half & 0xFFFFu);
            uint32x4 u;
#pragma unroll
            for (int q = 0; q < 4; ++q)
                u[q] = (((w16 >> (4 * q)) & 0xFu) * 0x00204081u) & 0x01010101u;
            i32x4 af = __builtin_bit_cast(i32x4, u);
            acc[r][0] = __builtin_amdgcn_mfma_i32_16x16x64_i8(af, v0, acc[r][0], 0, 0, 0);
            acc[r][1] = __builtin_amdgcn_mfma_i32_16x16x64_i8(af, v1, acc[r][1], 0, 0, 0);
            acc[r][2] = __builtin_amdgcn_mfma_i32_16x16x64_i8(af, v2, acc[r][2], 0, 0, 0);
        }
    };

    for (int T = 0; T < 32; T += 4) {
        dostep(mA, bA0, bA1, bA2);
        if (T + 4 < 32) LOADSET(A, T + 4)
        dostep(mB, bB0, bB1, bB2);
        if (T + 5 < 32) LOADSET(B, T + 5)
        dostep(mC, bC0, bC1, bC2);
        if (T + 6 < 32) LOADSET(C, T + 6)
        dostep(mD, bD0, bD1, bD2);
        if (T + 7 < 32) LOADSET(D, T + 7)
    }
#undef DECLSET
#undef LOADSET

    // merge kg=1 partials into kg=0 via LDS
    __syncthreads();
    if (kg == 1) {
        unsigned char* dst = lds + cg * 12288 + lane * 192;
#pragma unroll
        for (int r = 0; r < 4; ++r)
#pragma unroll
            for (int pl = 0; pl < 3; ++pl)
                *(i32x4*)(dst + (r * 3 + pl) * 16) = acc[r][pl];
    }
    __syncthreads();
    if (kg == 0) {
        const unsigned char* s2 = lds + cg * 12288 + lane * 192;
#pragma unroll
        for (int r = 0; r < 4; ++r)
#pragma unroll
            for (int pl = 0; pl < 3; ++pl) {
                i32x4 v = *(const i32x4*)(s2 + (r * 3 + pl) * 16);
#pragma unroll
                for (int q = 0; q < 4; ++q) acc[r][pl][q] += v[q];
            }

        const int o = cg * 16 + (lane & 15);
#pragma unroll
        for (int r = 0; r < 4; ++r) {
#pragma unroll
            for (int q = 0; q < 4; ++q) {
                double S = (double)acc[r][0][q] + 256.0 * (double)acc[r][1][q]
                         + 65536.0 * (double)acc[r][2][q];     // exact integer
                int i = rt * 64 + r * 16 + (lane >> 4) * 4 + q;  // C/D row map (m89)
                size_t oi = ((size_t)b * GN + i) * FOUT + o;
                out[oi] = S < 0.0 ? 1.0f : 0.0f;
                if (fabs(S) <= 2048.0) {
                    unsigned int idx = atomicAdd(&nflag, 1u);
                    if (idx < 128) flagbuf[idx] = ((unsigned int)i << 6) | (unsigned int)o;
                }
            }
        }
    }

    // ---- in-block exact fixup (expected ~0.2 items/block) ----
    __syncthreads();
    unsigned int nf = nflag;
    if (nf > 128) nf = 128;
    for (unsigned int f = 0; f < nf; ++f) {
        unsigned int e = flagbuf[f];
        int o = e & 63;
        int i = (int)(e >> 6);
        int row16 = i & 15, r = (i >> 4) & 3;
        int s = tid >> 3, lg = (tid >> 1) & 3, hf = tid & 1;
        unsigned long long w = tmask[((size_t)rt * 64 + s) * 64 + (lg * 16 + row16)];
        double ps = 0.0;
        const double* hwc = hW + ((size_t)b * GN + s * 64 + lg * 16) * FOUT + o;
#pragma unroll
        for (int jj = hf * 8; jj < hf * 8 + 8; ++jj) {
            if ((w >> (r * 16 + jj)) & 1ull)
                ps += hwc[(size_t)jj * FOUT];
        }
#pragma unroll
        for (int d = 32; d >= 1; d >>= 1) ps += __shfl_down(ps, d, 64);
        if (lane == 0) fred[wv] = ps;
        __syncthreads();
        if (tid == 0) {
            double tot = ((fred[0] + fred[1]) + (fred[2] + fred[3]))
                       + ((fred[4] + fred[5]) + (fred[6] + fred[7]));
            out[((size_t)b * GN + i) * FOUT + o] = tot < 0.0 ? 1.0f : 0.0f;
        }
        __syncthreads();
    }
}

extern "C" void kernel_launch(void* const* d_in, const int* in_sizes, int n_in,
                              void* d_out, int out_size, void* d_ws, size_t ws_size,
                              hipStream_t stream) {
    const float* h   = (const float*)d_in[0];   // [4,4096,128]
    const int*   adj = (const int*)d_in[1];     // [4096,4096]
    const float* W   = (const float*)d_in[2];   // [128,64]
    float* out = (float*)d_out;                 // [4,4096,64] f32

    char* ws = (char*)d_ws;
    double* hW                = (double*)ws;                          // 8 MB @ 0
    unsigned char* Bp         = (unsigned char*)(ws + 8388608);       // 3 MB @ 8M
    unsigned long long* tmask = (unsigned long long*)(ws + 12582912); // 2 MB @ 12M

    pack_kernel<<<1024, 256, 0, stream>>>(adj, tmask);
    hwrepack_kernel<<<1024, 256, 0, stream>>>(h, W, hW, Bp);
    gemm_kernel<<<256, 512, 0, stream>>>(Bp, tmask, hW, out);
}